// Round 13
// baseline (967.100 us; speedup 1.0000x reference)
//
#include <hip/hip_runtime.h>
#include <math.h>

typedef float f4 __attribute__((ext_vector_type(4)));
typedef float f2 __attribute__((ext_vector_type(2)));
typedef float f32x4 __attribute__((ext_vector_type(4)));
typedef _Float16 h8 __attribute__((ext_vector_type(8)));

constexpr int B_ = 4, C_ = 96, T_ = 320, F_ = 256;
constexpr int TF_ = T_ * F_;          // 81920
constexpr float EPS_ = 1e-5f;
constexpr size_t QH_ = (size_t)C_ * TF_;   // 7,864,320 elems per (C,T,F) unit

// W-split scratch layout (f16 elems, appended after the G*3 data units):
constexpr int WHF = 0, WLF = 27648, WHT = 55296, WLT = 73728,
              WHP = 92160, WLP = 101376, WTOT = 110592;

// ---------------------------------------------------------------------------
// One-time prep: split W into hi/lo f16; precompute BN (sc, sh) per channel.
// ---------------------------------------------------------------------------
__global__ __launch_bounds__(256)
void prep_kernel(const float* __restrict__ Wf, const float* __restrict__ Wt,
                 const float* __restrict__ Wp,
                 const float* __restrict__ bf, const float* __restrict__ gf,
                 const float* __restrict__ bef, const float* __restrict__ mf,
                 const float* __restrict__ vf,
                 const float* __restrict__ bt, const float* __restrict__ gt,
                 const float* __restrict__ bet, const float* __restrict__ mt,
                 const float* __restrict__ vt,
                 const float* __restrict__ bp, const float* __restrict__ gp,
                 const float* __restrict__ bep, const float* __restrict__ mp,
                 const float* __restrict__ vp,
                 _Float16* __restrict__ wsp, float* __restrict__ scsh)
{
    const int gtid = blockIdx.x * 256 + threadIdx.x;
    const int gsz  = gridDim.x * 256;
    for (int i = gtid; i < 27648; i += gsz) {
        const float w = Wf[i]; const _Float16 h = (_Float16)w;
        wsp[WHF + i] = h; wsp[WLF + i] = (_Float16)(w - (float)h);
    }
    for (int i = gtid; i < 18432; i += gsz) {
        const float w = Wt[i]; const _Float16 h = (_Float16)w;
        wsp[WHT + i] = h; wsp[WLT + i] = (_Float16)(w - (float)h);
    }
    for (int i = gtid; i < 9216; i += gsz) {
        const float w = Wp[i]; const _Float16 h = (_Float16)w;
        wsp[WHP + i] = h; wsp[WLP + i] = (_Float16)(w - (float)h);
    }
    if (gtid < 288) {
        const float sc = gf[gtid] * rsqrtf(vf[gtid] + EPS_);
        scsh[2 * gtid] = sc;
        scsh[2 * gtid + 1] = fmaf(bf[gtid] - mf[gtid], sc, bef[gtid]);
    } else if (gtid < 480) {
        const int i = gtid - 288;
        const float sc = gt[i] * rsqrtf(vt[i] + EPS_);
        scsh[576 + 2 * i] = sc;
        scsh[576 + 2 * i + 1] = fmaf(bt[i] - mt[i], sc, bet[i]);
    } else if (gtid < 576) {
        const int i = gtid - 480;
        const float sc = gp[i] * rsqrtf(vp[i] + EPS_);
        scsh[960 + 2 * i] = sc;
        scsh[960 + 2 * i + 1] = fmaf(bp[i] - mp[i], sc, bep[i]);
    }
}

// ---------------------------------------------------------------------------
// Fused conv_f + conv_t (round-11 proven body: inline W loads, compiler-
// scheduled — the round-12 manual double-buffer spilled to scratch).
// Stage X hi/lo once per 64-p tile; loop 5 output groups (3 -> yf, 2 -> yt).
// acc += wh*xh + wl*xh + wh*xl  (drop xl*wl; fp32-accurate).
// 25.6 KB LDS, ~64 VGPR -> __launch_bounds__(256,6): 6 blocks/CU.
// ---------------------------------------------------------------------------
__global__ __launch_bounds__(256, 6)
void conv_ft(const float* __restrict__ x, const _Float16* __restrict__ wsp,
             const float* __restrict__ scsh,
             const float* __restrict__ aPf, const float* __restrict__ aPt,
             _Float16* __restrict__ yf, _Float16* __restrict__ yt,
             int bsx, int bsyf, int bsyt)
{
    constexpr int LS = 200;
    extern __shared__ _Float16 ldsh[];
    _Float16* Xs = ldsh;                   // [64][200]: 0-95 hi, 96-191 lo

    x  += (size_t)blockIdx.y * bsx;
    yf += (size_t)blockIdx.y * bsyf;
    yt += (size_t)blockIdx.y * bsyt;

    const int tid = threadIdx.x;
    const int p0  = blockIdx.x * 64;

    // ---- stage X hi/lo: gather 8 k per p, lanes coalesced on p ----
    const float* xg = x + p0;
    for (int e = tid; e < 64 * 12; e += 256) {
        const int p = e & 63, k0 = (e >> 6) * 8;
        const float* xp = xg + (size_t)k0 * TF_ + p;
        h8 hv, lv;
#pragma unroll
        for (int j = 0; j < 8; ++j) {
            const float xv = xp[(size_t)j * TF_];
            const _Float16 xh = (_Float16)xv;
            hv[j] = xh;
            lv[j] = (_Float16)(xv - (float)xh);
        }
        *(h8*)&Xs[p * LS + k0]      = hv;
        *(h8*)&Xs[p * LS + 96 + k0] = lv;
    }

    const int lane = tid & 63, wid = tid >> 6;
    const int l16 = lane & 15, lg = lane >> 4;
    const int wm = wid >> 1, wn = wid & 1;       // 2x2 wave grid
    const float af_ = aPf[0], at_ = aPt[0];
    __syncthreads();

#pragma unroll 1
    for (int cg = 0; cg < 5; ++cg) {
        const _Float16 *Wh, *Wl; const float* ss; float a; _Float16* yo;
        if (cg < 3) {
            Wh = wsp + WHF + cg * 9216;  Wl = wsp + WLF + cg * 9216;
            ss = scsh + cg * 192;        a = af_;
            yo = yf + (size_t)cg * QH_;
        } else {
            const int c2 = cg - 3;
            Wh = wsp + WHT + c2 * 9216;  Wl = wsp + WLT + c2 * 9216;
            ss = scsh + 576 + c2 * 192;  a = at_;
            yo = yt + (size_t)c2 * QH_;
        }

        f32x4 acc[3][2];
#pragma unroll
        for (int m = 0; m < 3; ++m)
#pragma unroll
            for (int n = 0; n < 2; ++n) acc[m][n] = (f32x4){0.f, 0.f, 0.f, 0.f};

#pragma unroll
        for (int kk = 0; kk < 3; ++kk) {
            h8 bfh[2], bfl[2];
#pragma unroll
            for (int n = 0; n < 2; ++n) {
                const int prow = (wn * 2 + n) * 16 + l16;
                bfh[n] = *(const h8*)&Xs[prow * LS + kk * 32 + lg * 8];
                bfl[n] = *(const h8*)&Xs[prow * LS + 96 + kk * 32 + lg * 8];
            }
#pragma unroll
            for (int m = 0; m < 3; ++m) {
                const int row = (wm * 3 + m) * 16 + l16;
                const h8 wh = *(const h8*)&Wh[row * 96 + kk * 32 + lg * 8];
                const h8 wl = *(const h8*)&Wl[row * 96 + kk * 32 + lg * 8];
#pragma unroll
                for (int n = 0; n < 2; ++n) {
                    acc[m][n] = __builtin_amdgcn_mfma_f32_16x16x32_f16(wh, bfh[n], acc[m][n], 0, 0, 0);
                    acc[m][n] = __builtin_amdgcn_mfma_f32_16x16x32_f16(wl, bfh[n], acc[m][n], 0, 0, 0);
                    acc[m][n] = __builtin_amdgcn_mfma_f32_16x16x32_f16(wh, bfl[n], acc[m][n], 0, 0, 0);
                }
            }
        }

#pragma unroll
        for (int m = 0; m < 3; ++m) {
#pragma unroll
            for (int r = 0; r < 4; ++r) {
                const int col = (wm * 3 + m) * 16 + lg * 4 + r;
                const f2 sp = *(const f2*)&ss[2 * col];
                _Float16* yr = yo + (size_t)col * TF_ + p0 + wn * 32 + l16;
#pragma unroll
                for (int n = 0; n < 2; ++n) {
                    const float v = fmaf(acc[m][n][r], sp[0], sp[1]);
                    yr[n * 16] = (_Float16)(v >= 0.f ? v : a * v);
                }
            }
        }
    }
}

// ---------------------------------------------------------------------------
// conv_p: f16 input (F groups, C, T), pre-split W, 160-p tiles, batched.
// ---------------------------------------------------------------------------
__global__ __launch_bounds__(256, 3)
void conv_p(const _Float16* __restrict__ x, const _Float16* __restrict__ wsp,
            const float* __restrict__ scsh, const float* __restrict__ aPp,
            _Float16* __restrict__ y, int bsx, int bsy)
{
    constexpr int LS = 104, PT = 160, NN = 5;
    extern __shared__ _Float16 ldsh[];
    _Float16* Xs = ldsh;                   // [160][104]

    x += (size_t)blockIdx.y * bsx;
    y += (size_t)blockIdx.y * bsy;

    const int tid = threadIdx.x;
    const int pt  = blockIdx.x & 1;
    const int g   = blockIdx.x >> 1;
    const int p0  = pt * PT;

    const _Float16* xg = x + (size_t)g * 96 * T_ + p0;
    for (int e = tid; e < PT * 12; e += 256) {
        const int p = e % PT, k0 = (e / PT) * 8;
        const _Float16* xp = xg + (size_t)k0 * T_ + p;
        h8 hv;
#pragma unroll
        for (int j = 0; j < 8; ++j) hv[j] = xp[(size_t)j * T_];
        *(h8*)&Xs[p * LS + k0] = hv;
    }

    const int lane = tid & 63, wid = tid >> 6;
    const int l16 = lane & 15, lg = lane >> 4;
    const int wm = wid >> 1, wn = wid & 1;
    const float a = aPp[0];
    const _Float16* Wh = wsp + WHP;
    const _Float16* Wl = wsp + WLP;
    const float* ss = scsh + 960;
    __syncthreads();

    f32x4 acc[3][NN];
#pragma unroll
    for (int m = 0; m < 3; ++m)
#pragma unroll
        for (int n = 0; n < NN; ++n) acc[m][n] = (f32x4){0.f, 0.f, 0.f, 0.f};

#pragma unroll
    for (int kk = 0; kk < 3; ++kk) {
        h8 bf[NN];
#pragma unroll
        for (int n = 0; n < NN; ++n)
            bf[n] = *(const h8*)&Xs[((wn * NN + n) * 16 + l16) * LS + kk * 32 + lg * 8];
#pragma unroll
        for (int m = 0; m < 3; ++m) {
            const int row = (wm * 3 + m) * 16 + l16;
            const h8 wh = *(const h8*)&Wh[row * 96 + kk * 32 + lg * 8];
            const h8 wl = *(const h8*)&Wl[row * 96 + kk * 32 + lg * 8];
#pragma unroll
            for (int n = 0; n < NN; ++n) {
                acc[m][n] = __builtin_amdgcn_mfma_f32_16x16x32_f16(wh, bf[n], acc[m][n], 0, 0, 0);
                acc[m][n] = __builtin_amdgcn_mfma_f32_16x16x32_f16(wl, bf[n], acc[m][n], 0, 0, 0);
            }
        }
    }

#pragma unroll
    for (int m = 0; m < 3; ++m) {
#pragma unroll
        for (int r = 0; r < 4; ++r) {
            const int col = (wm * 3 + m) * 16 + lg * 4 + r;
            const f2 sp = *(const f2*)&ss[2 * col];
            _Float16* yr = y + ((size_t)g * 96 + col) * T_ + p0 + wn * NN * 16 + l16;
#pragma unroll
            for (int n = 0; n < NN; ++n) {
                const float v = fmaf(acc[m][n][r], sp[0], sp[1]);
                yr[n * 16] = (_Float16)(v >= 0.f ? v : a * v);
            }
        }
    }
}

// ---------------------------------------------------------------------------
// Merged transpose A: per batch 2 slabs (z = b*2 + t).
//   t=0: fout (unit 3b+0) -> foutT (unit 3b+1)
//   t=1: th2 q-half (doh)  -> tqT   (unit 3b+2)
// ---------------------------------------------------------------------------
__global__ __launch_bounds__(256)
void transpose_trA(const _Float16* __restrict__ doh, _Float16* __restrict__ wsh)
{
    const int b = blockIdx.z >> 1, t = blockIdx.z & 1;
    const _Float16* in  = t ? doh + (size_t)b * 2 * QH_
                            : wsh + (size_t)b * 3 * QH_;
    _Float16*       out = t ? wsh + (size_t)b * 3 * QH_ + 2 * QH_
                            : wsh + (size_t)b * 3 * QH_ + QH_;
    __shared__ _Float16 tile[32][34];
    const int n0 = blockIdx.x * 32, m0 = blockIdx.y * 32;
    const int tx = threadIdx.x, ty = threadIdx.y;
#pragma unroll
    for (int i = 0; i < 32; i += 8)
        tile[ty + i][tx] = in[(size_t)(n0 + ty + i) * F_ + (m0 + tx)];
    __syncthreads();
#pragma unroll
    for (int i = 0; i < 32; i += 8)
        out[(size_t)(m0 + ty + i) * (C_ * T_) + (n0 + tx)] = tile[tx][ty + i];
}

// ---------------------------------------------------------------------------
// Transpose B: th2 k-half (doh+QH) -> tkT (unit 3b+0; fout dead after trA).
// ---------------------------------------------------------------------------
__global__ __launch_bounds__(256)
void transpose_trB(const _Float16* __restrict__ doh, _Float16* __restrict__ wsh)
{
    const int b = blockIdx.z;
    const _Float16* in  = doh + (size_t)b * 2 * QH_ + QH_;
    _Float16*       out = wsh + (size_t)b * 3 * QH_;
    __shared__ _Float16 tile[32][34];
    const int n0 = blockIdx.x * 32, m0 = blockIdx.y * 32;
    const int tx = threadIdx.x, ty = threadIdx.y;
#pragma unroll
    for (int i = 0; i < 32; i += 8)
        tile[ty + i][tx] = in[(size_t)(n0 + ty + i) * F_ + (m0 + tx)];
    __syncthreads();
#pragma unroll
    for (int i = 0; i < 32; i += 8)
        out[(size_t)(m0 + ty + i) * (C_ * T_) + (n0 + tx)] = tile[tx][ty + i];
}

// ---------------------------------------------------------------------------
// f16 in + f32 residual -> f32 out transpose (final step).
// ---------------------------------------------------------------------------
__global__ __launch_bounds__(256)
void transpose_hf_res(const _Float16* __restrict__ in, const float* __restrict__ res,
                      float* __restrict__ out, int Mo, int No, int si, int sr, int so)
{
    __shared__ _Float16 tile[32][34];
    in  += (size_t)blockIdx.z * si;
    res += (size_t)blockIdx.z * sr;
    out += (size_t)blockIdx.z * so;
    const int n0 = blockIdx.x * 32, m0 = blockIdx.y * 32;
    const int tx = threadIdx.x, ty = threadIdx.y;
#pragma unroll
    for (int i = 0; i < 32; i += 8)
        tile[ty + i][tx] = in[(size_t)(n0 + ty + i) * Mo + (m0 + tx)];
    __syncthreads();
#pragma unroll
    for (int i = 0; i < 32; i += 8) {
        const size_t oidx = (size_t)(m0 + ty + i) * No + (n0 + tx);
        out[oidx] = (float)tile[tx][ty + i] + res[oidx];
    }
}

// ---------------------------------------------------------------------------
// MFMA f16 fused attention — all-f16 I/O, batched.  O may alias Q (in-place):
// each block reads Q only in its own output strip, written after all reads.
// ---------------------------------------------------------------------------
template<int MODE>
__global__ __launch_bounds__(256, 2)
void attn_mfma(const _Float16* __restrict__ Qb, const _Float16* __restrict__ Kb,
               const _Float16* __restrict__ Vb, _Float16* __restrict__ Ob,
               int qs, int ks, int vs, int os)
{
    constexpr int NY  = (MODE == 0) ? 256 : 320;
    constexpr int LD  = (MODE == 0) ? TF_ : T_;
    constexpr int NT  = NY / 16;
    constexpr int NYK = NY / 32;
    constexpr int KS  = 104;
    constexpr int VPS = NY + 24;
    constexpr int KVH = (NY * KS > 96 * VPS) ? NY * KS : 96 * VPS;
    constexpr int NG  = (MODE == 0) ? T_ : F_;
    constexpr int GOFF = (MODE == 0) ? F_ : C_ * T_;

    extern __shared__ _Float16 ldsh[];
    _Float16* KV = ldsh;                 // Kt[NY][KS] -> V[96][VPS]
    _Float16* Pw = ldsh + KVH;           // [4][16][40]

    const int lb    = blockIdx.y;
    const int strip = blockIdx.x / NG;
    const int grp   = blockIdx.x % NG;
    const int m0    = strip * 64;
    const size_t off = (size_t)grp * GOFF;
    const _Float16* Q = Qb + (size_t)lb * qs + off;
    const _Float16* K = Kb + (size_t)lb * ks + off;
    const _Float16* V = Vb + (size_t)lb * vs + off;
    _Float16*       O = Ob + (size_t)lb * os + off;

    const int tid  = threadIdx.x;
    const int lane = tid & 63, wid = tid >> 6;
    const int l16  = lane & 15, lg = lane >> 4;
    const int mw   = wid * 16;
    const float scale = 0.10206207261596575f;   // 1/sqrt(96)

    for (int e = tid; e < NY * 12; e += 256) {
        const int yy = e % NY, k0 = (e / NY) * 8;
        const _Float16* kp = K + (size_t)k0 * LD + yy;
        h8 hv;
#pragma unroll
        for (int j = 0; j < 8; ++j) hv[j] = kp[(size_t)j * LD];
        *(h8*)&KV[yy * KS + k0] = hv;
    }

    h8 aQ[3];
#pragma unroll
    for (int kk = 0; kk < 3; ++kk) {
        const _Float16* qp = Q + (size_t)(kk * 32 + lg * 8) * LD + m0 + mw + l16;
#pragma unroll
        for (int j = 0; j < 8; ++j) aQ[kk][j] = qp[(size_t)j * LD];
    }
    __syncthreads();

    f32x4 sacc[NT];
#pragma unroll
    for (int t = 0; t < NT; ++t) sacc[t] = (f32x4){0.f, 0.f, 0.f, 0.f};
#pragma unroll
    for (int kk = 0; kk < 3; ++kk) {
#pragma unroll
        for (int t = 0; t < NT; ++t) {
            const h8 bK = *(const h8*)&KV[(t * 16 + l16) * KS + kk * 32 + lg * 8];
            sacc[t] = __builtin_amdgcn_mfma_f32_16x16x32_f16(aQ[kk], bK, sacc[t], 0, 0, 0);
        }
    }

#pragma unroll
    for (int r = 0; r < 4; ++r) {
        float mx = sacc[0][r];
#pragma unroll
        for (int t = 1; t < NT; ++t) mx = fmaxf(mx, sacc[t][r]);
        for (int d = 1; d < 16; d <<= 1) mx = fmaxf(mx, __shfl_xor(mx, d));
        float pv[NT];
        float sum = 0.f;
#pragma unroll
        for (int t = 0; t < NT; ++t) {
            pv[t] = __expf((sacc[t][r] - mx) * scale); sum += pv[t];
        }
        for (int d = 1; d < 16; d <<= 1) sum += __shfl_xor(sum, d);
        const float inv = 1.f / sum;
#pragma unroll
        for (int t = 0; t < NT; ++t) sacc[t][r] = pv[t] * inv;
    }
    __syncthreads();

    constexpr int NY8 = NY / 8;
    for (int e = tid; e < 96 * NY8; e += 256) {
        const int c = e / NY8, y8 = e - c * NY8;
        *(h8*)&KV[c * VPS + y8 * 8] = *(const h8*)(V + (size_t)c * LD + y8 * 8);
    }
    __syncthreads();

    _Float16* Pme = Pw + wid * 640;      // [16][40]
    f32x4 oacc[6];
#pragma unroll
    for (int ct = 0; ct < 6; ++ct) oacc[ct] = (f32x4){0.f, 0.f, 0.f, 0.f};

#pragma unroll
    for (int yk = 0; yk < NYK; ++yk) {
#pragma unroll
        for (int h = 0; h < 2; ++h)
#pragma unroll
            for (int r = 0; r < 4; ++r)
                Pme[(lg * 4 + r) * 40 + h * 16 + l16] = (_Float16)sacc[2 * yk + h][r];
        const h8 pf = *(const h8*)&Pme[l16 * 40 + lg * 8];   // in-wave DS order
#pragma unroll
        for (int ct = 0; ct < 6; ++ct) {
            const h8 av = *(const h8*)&KV[(ct * 16 + l16) * VPS + yk * 32 + lg * 8];
            oacc[ct] = __builtin_amdgcn_mfma_f32_16x16x32_f16(av, pf, oacc[ct], 0, 0, 0);
        }
    }
#pragma unroll
    for (int ct = 0; ct < 6; ++ct)
#pragma unroll
        for (int r = 0; r < 4; ++r)
            O[(size_t)(ct * 16 + lg * 4 + r) * LD + m0 + mw + l16] = (_Float16)oacc[ct][r];
}

// ---------------------------------------------------------------------------
extern "C" void kernel_launch(void* const* d_in, const int* in_sizes, int n_in,
                              void* d_out, int out_size, void* d_ws, size_t ws_size,
                              hipStream_t stream)
{
    const float* inp = (const float*)d_in[0];
    const float* W_f = (const float*)d_in[1];  const float* b_f = (const float*)d_in[2];
    const float* g_f = (const float*)d_in[3];  const float* be_f = (const float*)d_in[4];
    const float* m_f = (const float*)d_in[5];  const float* v_f = (const float*)d_in[6];
    const float* a_f = (const float*)d_in[7];
    const float* W_t = (const float*)d_in[8];  const float* b_t = (const float*)d_in[9];
    const float* g_t = (const float*)d_in[10]; const float* be_t = (const float*)d_in[11];
    const float* m_t = (const float*)d_in[12]; const float* v_t = (const float*)d_in[13];
    const float* a_t = (const float*)d_in[14];
    const float* W_p = (const float*)d_in[15]; const float* b_p = (const float*)d_in[16];
    const float* g_p = (const float*)d_in[17]; const float* be_p = (const float*)d_in[18];
    const float* m_p = (const float*)d_in[19]; const float* v_p = (const float*)d_in[20];
    const float* a_p = (const float*)d_in[21];

    hipFuncSetAttribute((const void*)conv_ft,
                        hipFuncAttributeMaxDynamicSharedMemorySize, 25600);
    hipFuncSetAttribute((const void*)conv_p,
                        hipFuncAttributeMaxDynamicSharedMemorySize, 33280);
    hipFuncSetAttribute((const void*)attn_mfma<0>,
                        hipFuncAttributeMaxDynamicSharedMemorySize, 58880);
    hipFuncSetAttribute((const void*)attn_mfma<1>,
                        hipFuncAttributeMaxDynamicSharedMemorySize, 71680);

    // Unit plan per batch b (f16 units of QH_ elems, stride 3*QH_):
    //  3b+0: fqkv Q -> fout (attn0 in-place) -> [trA] -> tkT -> tmp
    //  3b+1: fqkv K -> foutT (trA)
    //  3b+2: fqkv V -> tqT (trA) -> tout (attn1 in-place)
    //  d_out slice (2 f16 units/batch): th2 q,k halves.
    constexpr int QH = (int)QH_;
    const size_t need4 = (size_t)12 * QH * 2 + (size_t)WTOT * 2 + 1152 * 4 + 4096;
    const int G = (ws_size >= need4) ? 4 : 2;     // batches per pass

    _Float16* wsh  = (_Float16*)d_ws;
    _Float16* wsp  = wsh + (size_t)3 * G * QH;    // W-split tail
    float*    scsh = (float*)(wsp + WTOT);

    prep_kernel<<<dim3(128), dim3(256), 0, stream>>>(
        W_f, W_t, W_p, b_f, g_f, be_f, m_f, v_f,
        b_t, g_t, be_t, m_t, v_t, b_p, g_p, be_p, m_p, v_p, wsp, scsh);

    for (int p = 0; p < B_ / G; ++p) {
        const float* xb  = inp + (size_t)p * G * QH;
        float*       dob = (float*)d_out + (size_t)p * G * QH;
        _Float16*    doh = (_Float16*)dob;        // th2 (2 units/batch)

        // 1. fused conv_f + conv_t: fqkv -> ws, th2 -> d_out slice
        conv_ft<<<dim3(1280, G), dim3(256), 25600, stream>>>(
            xb, wsp, scsh, a_f, a_t, wsh, doh, QH, 3 * QH, 2 * QH);
        // 2. f-attention, O in-place over Q third
        attn_mfma<0><<<dim3(T_ * (F_ / 64), G), dim3(256), 58880, stream>>>(
            wsh, wsh + QH_, wsh + 2 * QH_, wsh, 3 * QH, 3 * QH, 3 * QH, 3 * QH);
        // 3. trA: fout -> foutT (3b+1), th2 q -> tqT (3b+2)
        transpose_trA<<<dim3(960, 8, 2 * G), dim3(32, 8), 0, stream>>>(doh, wsh);
        // 4. trB: th2 k -> tkT (3b+0; fout dead)
        transpose_trB<<<dim3(960, 8, G), dim3(32, 8), 0, stream>>>(doh, wsh);
        // 5. t-attention: Q=tqT(3b+2), K=tkT(3b+0), V=foutT(3b+1), O in-place
        attn_mfma<1><<<dim3(F_ * (T_ / 64), G), dim3(256), 71680, stream>>>(
            wsh + 2 * QH_, wsh, wsh + QH_, wsh + 2 * QH_,
            3 * QH, 3 * QH, 3 * QH, 3 * QH);
        // 6. conv_p(tout = 3b+2) -> tmp (3b+0; tkT dead)
        conv_p<<<dim3(F_ * 2, G), dim3(256), 33280, stream>>>(
            wsh + 2 * QH_, wsp, scsh, a_p, wsh, 3 * QH, 3 * QH);
        // 7. out = transpose(tmp) + inp (th2 dead)
        transpose_hf_res<<<dim3(8, 960, G), dim3(32, 8), 0, stream>>>(
            wsh, xb, dob, C_ * T_, F_, 3 * QH, QH, QH);
    }
}

// Round 14
// 737.119 us; speedup vs baseline: 1.3120x; 1.3120x over previous
//
#include <hip/hip_runtime.h>
#include <math.h>

typedef float f4 __attribute__((ext_vector_type(4)));
typedef float f2 __attribute__((ext_vector_type(2)));
typedef float f32x4 __attribute__((ext_vector_type(4)));
typedef _Float16 h8 __attribute__((ext_vector_type(8)));

constexpr int B_ = 4, C_ = 96, T_ = 320, F_ = 256;
constexpr int TF_ = T_ * F_;          // 81920
constexpr float EPS_ = 1e-5f;
constexpr size_t QH_ = (size_t)C_ * TF_;   // 7,864,320 elems per (C,T,F) unit

// W-split scratch layout (f16 elems, appended after the G*3 data units):
constexpr int WHF = 0, WLF = 27648, WHT = 55296, WLT = 73728,
              WHP = 92160, WLP = 101376, WTOT = 110592;

// ---------------------------------------------------------------------------
// One-time prep: split W into hi/lo f16; precompute BN (sc, sh) per channel.
// ---------------------------------------------------------------------------
__global__ __launch_bounds__(256)
void prep_kernel(const float* __restrict__ Wf, const float* __restrict__ Wt,
                 const float* __restrict__ Wp,
                 const float* __restrict__ bf, const float* __restrict__ gf,
                 const float* __restrict__ bef, const float* __restrict__ mf,
                 const float* __restrict__ vf,
                 const float* __restrict__ bt, const float* __restrict__ gt,
                 const float* __restrict__ bet, const float* __restrict__ mt,
                 const float* __restrict__ vt,
                 const float* __restrict__ bp, const float* __restrict__ gp,
                 const float* __restrict__ bep, const float* __restrict__ mp,
                 const float* __restrict__ vp,
                 _Float16* __restrict__ wsp, float* __restrict__ scsh)
{
    const int gtid = blockIdx.x * 256 + threadIdx.x;
    const int gsz  = gridDim.x * 256;
    for (int i = gtid; i < 27648; i += gsz) {
        const float w = Wf[i]; const _Float16 h = (_Float16)w;
        wsp[WHF + i] = h; wsp[WLF + i] = (_Float16)(w - (float)h);
    }
    for (int i = gtid; i < 18432; i += gsz) {
        const float w = Wt[i]; const _Float16 h = (_Float16)w;
        wsp[WHT + i] = h; wsp[WLT + i] = (_Float16)(w - (float)h);
    }
    for (int i = gtid; i < 9216; i += gsz) {
        const float w = Wp[i]; const _Float16 h = (_Float16)w;
        wsp[WHP + i] = h; wsp[WLP + i] = (_Float16)(w - (float)h);
    }
    if (gtid < 288) {
        const float sc = gf[gtid] * rsqrtf(vf[gtid] + EPS_);
        scsh[2 * gtid] = sc;
        scsh[2 * gtid + 1] = fmaf(bf[gtid] - mf[gtid], sc, bef[gtid]);
    } else if (gtid < 480) {
        const int i = gtid - 288;
        const float sc = gt[i] * rsqrtf(vt[i] + EPS_);
        scsh[576 + 2 * i] = sc;
        scsh[576 + 2 * i + 1] = fmaf(bt[i] - mt[i], sc, bet[i]);
    } else if (gtid < 576) {
        const int i = gtid - 480;
        const float sc = gp[i] * rsqrtf(vp[i] + EPS_);
        scsh[960 + 2 * i] = sc;
        scsh[960 + 2 * i + 1] = fmaf(bp[i] - mp[i], sc, bep[i]);
    }
}

// ---------------------------------------------------------------------------
// Fused conv_f + conv_t — EXACT round-11 proven config: inline W loads,
// compiler-scheduled, __launch_bounds__(256,3) -> 64 VGPR, zero spill.
// (Round-12 manual double-buffer spilled; round-13 bounds=6 clamped VGPR to 40
// and spilled. Do not fight the allocator.)
// ---------------------------------------------------------------------------
__global__ __launch_bounds__(256, 3)
void conv_ft(const float* __restrict__ x, const _Float16* __restrict__ wsp,
             const float* __restrict__ scsh,
             const float* __restrict__ aPf, const float* __restrict__ aPt,
             _Float16* __restrict__ yf, _Float16* __restrict__ yt,
             int bsx, int bsyf, int bsyt)
{
    constexpr int LS = 200;
    extern __shared__ _Float16 ldsh[];
    _Float16* Xs = ldsh;                   // [64][200]: 0-95 hi, 96-191 lo

    x  += (size_t)blockIdx.y * bsx;
    yf += (size_t)blockIdx.y * bsyf;
    yt += (size_t)blockIdx.y * bsyt;

    const int tid = threadIdx.x;
    const int p0  = blockIdx.x * 64;

    // ---- stage X hi/lo: gather 8 k per p, lanes coalesced on p ----
    const float* xg = x + p0;
    for (int e = tid; e < 64 * 12; e += 256) {
        const int p = e & 63, k0 = (e >> 6) * 8;
        const float* xp = xg + (size_t)k0 * TF_ + p;
        h8 hv, lv;
#pragma unroll
        for (int j = 0; j < 8; ++j) {
            const float xv = xp[(size_t)j * TF_];
            const _Float16 xh = (_Float16)xv;
            hv[j] = xh;
            lv[j] = (_Float16)(xv - (float)xh);
        }
        *(h8*)&Xs[p * LS + k0]      = hv;
        *(h8*)&Xs[p * LS + 96 + k0] = lv;
    }

    const int lane = tid & 63, wid = tid >> 6;
    const int l16 = lane & 15, lg = lane >> 4;
    const int wm = wid >> 1, wn = wid & 1;       // 2x2 wave grid
    const float af_ = aPf[0], at_ = aPt[0];
    __syncthreads();

#pragma unroll 1
    for (int cg = 0; cg < 5; ++cg) {
        const _Float16 *Wh, *Wl; const float* ss; float a; _Float16* yo;
        if (cg < 3) {
            Wh = wsp + WHF + cg * 9216;  Wl = wsp + WLF + cg * 9216;
            ss = scsh + cg * 192;        a = af_;
            yo = yf + (size_t)cg * QH_;
        } else {
            const int c2 = cg - 3;
            Wh = wsp + WHT + c2 * 9216;  Wl = wsp + WLT + c2 * 9216;
            ss = scsh + 576 + c2 * 192;  a = at_;
            yo = yt + (size_t)c2 * QH_;
        }

        f32x4 acc[3][2];
#pragma unroll
        for (int m = 0; m < 3; ++m)
#pragma unroll
            for (int n = 0; n < 2; ++n) acc[m][n] = (f32x4){0.f, 0.f, 0.f, 0.f};

#pragma unroll
        for (int kk = 0; kk < 3; ++kk) {
            h8 bfh[2], bfl[2];
#pragma unroll
            for (int n = 0; n < 2; ++n) {
                const int prow = (wn * 2 + n) * 16 + l16;
                bfh[n] = *(const h8*)&Xs[prow * LS + kk * 32 + lg * 8];
                bfl[n] = *(const h8*)&Xs[prow * LS + 96 + kk * 32 + lg * 8];
            }
#pragma unroll
            for (int m = 0; m < 3; ++m) {
                const int row = (wm * 3 + m) * 16 + l16;
                const h8 wh = *(const h8*)&Wh[row * 96 + kk * 32 + lg * 8];
                const h8 wl = *(const h8*)&Wl[row * 96 + kk * 32 + lg * 8];
#pragma unroll
                for (int n = 0; n < 2; ++n) {
                    acc[m][n] = __builtin_amdgcn_mfma_f32_16x16x32_f16(wh, bfh[n], acc[m][n], 0, 0, 0);
                    acc[m][n] = __builtin_amdgcn_mfma_f32_16x16x32_f16(wl, bfh[n], acc[m][n], 0, 0, 0);
                    acc[m][n] = __builtin_amdgcn_mfma_f32_16x16x32_f16(wh, bfl[n], acc[m][n], 0, 0, 0);
                }
            }
        }

#pragma unroll
        for (int m = 0; m < 3; ++m) {
#pragma unroll
            for (int r = 0; r < 4; ++r) {
                const int col = (wm * 3 + m) * 16 + lg * 4 + r;
                const f2 sp = *(const f2*)&ss[2 * col];
                _Float16* yr = yo + (size_t)col * TF_ + p0 + wn * 32 + l16;
#pragma unroll
                for (int n = 0; n < 2; ++n) {
                    const float v = fmaf(acc[m][n][r], sp[0], sp[1]);
                    yr[n * 16] = (_Float16)(v >= 0.f ? v : a * v);
                }
            }
        }
    }
}

// ---------------------------------------------------------------------------
// conv_p: f16 input (F groups, C, T), pre-split W, 160-p tiles, batched.
// ---------------------------------------------------------------------------
__global__ __launch_bounds__(256, 3)
void conv_p(const _Float16* __restrict__ x, const _Float16* __restrict__ wsp,
            const float* __restrict__ scsh, const float* __restrict__ aPp,
            _Float16* __restrict__ y, int bsx, int bsy)
{
    constexpr int LS = 104, PT = 160, NN = 5;
    extern __shared__ _Float16 ldsh[];
    _Float16* Xs = ldsh;                   // [160][104]

    x += (size_t)blockIdx.y * bsx;
    y += (size_t)blockIdx.y * bsy;

    const int tid = threadIdx.x;
    const int pt  = blockIdx.x & 1;
    const int g   = blockIdx.x >> 1;
    const int p0  = pt * PT;

    const _Float16* xg = x + (size_t)g * 96 * T_ + p0;
    for (int e = tid; e < PT * 12; e += 256) {
        const int p = e % PT, k0 = (e / PT) * 8;
        const _Float16* xp = xg + (size_t)k0 * T_ + p;
        h8 hv;
#pragma unroll
        for (int j = 0; j < 8; ++j) hv[j] = xp[(size_t)j * T_];
        *(h8*)&Xs[p * LS + k0] = hv;
    }

    const int lane = tid & 63, wid = tid >> 6;
    const int l16 = lane & 15, lg = lane >> 4;
    const int wm = wid >> 1, wn = wid & 1;
    const float a = aPp[0];
    const _Float16* Wh = wsp + WHP;
    const _Float16* Wl = wsp + WLP;
    const float* ss = scsh + 960;
    __syncthreads();

    f32x4 acc[3][NN];
#pragma unroll
    for (int m = 0; m < 3; ++m)
#pragma unroll
        for (int n = 0; n < NN; ++n) acc[m][n] = (f32x4){0.f, 0.f, 0.f, 0.f};

#pragma unroll
    for (int kk = 0; kk < 3; ++kk) {
        h8 bf[NN];
#pragma unroll
        for (int n = 0; n < NN; ++n)
            bf[n] = *(const h8*)&Xs[((wn * NN + n) * 16 + l16) * LS + kk * 32 + lg * 8];
#pragma unroll
        for (int m = 0; m < 3; ++m) {
            const int row = (wm * 3 + m) * 16 + l16;
            const h8 wh = *(const h8*)&Wh[row * 96 + kk * 32 + lg * 8];
            const h8 wl = *(const h8*)&Wl[row * 96 + kk * 32 + lg * 8];
#pragma unroll
            for (int n = 0; n < NN; ++n) {
                acc[m][n] = __builtin_amdgcn_mfma_f32_16x16x32_f16(wh, bf[n], acc[m][n], 0, 0, 0);
                acc[m][n] = __builtin_amdgcn_mfma_f32_16x16x32_f16(wl, bf[n], acc[m][n], 0, 0, 0);
            }
        }
    }

#pragma unroll
    for (int m = 0; m < 3; ++m) {
#pragma unroll
        for (int r = 0; r < 4; ++r) {
            const int col = (wm * 3 + m) * 16 + lg * 4 + r;
            const f2 sp = *(const f2*)&ss[2 * col];
            _Float16* yr = y + ((size_t)g * 96 + col) * T_ + p0 + wn * NN * 16 + l16;
#pragma unroll
            for (int n = 0; n < NN; ++n) {
                const float v = fmaf(acc[m][n][r], sp[0], sp[1]);
                yr[n * 16] = (_Float16)(v >= 0.f ? v : a * v);
            }
        }
    }
}

// ---------------------------------------------------------------------------
// Merged transpose A: per batch 2 slabs (z = b*2 + t).
//   t=0: fout (unit 3b+0) -> foutT (unit 3b+1)
//   t=1: th2 q-half (doh)  -> tqT   (unit 3b+2)
// ---------------------------------------------------------------------------
__global__ __launch_bounds__(256)
void transpose_trA(const _Float16* __restrict__ doh, _Float16* __restrict__ wsh)
{
    const int b = blockIdx.z >> 1, t = blockIdx.z & 1;
    const _Float16* in  = t ? doh + (size_t)b * 2 * QH_
                            : wsh + (size_t)b * 3 * QH_;
    _Float16*       out = t ? wsh + (size_t)b * 3 * QH_ + 2 * QH_
                            : wsh + (size_t)b * 3 * QH_ + QH_;
    __shared__ _Float16 tile[32][34];
    const int n0 = blockIdx.x * 32, m0 = blockIdx.y * 32;
    const int tx = threadIdx.x, ty = threadIdx.y;
#pragma unroll
    for (int i = 0; i < 32; i += 8)
        tile[ty + i][tx] = in[(size_t)(n0 + ty + i) * F_ + (m0 + tx)];
    __syncthreads();
#pragma unroll
    for (int i = 0; i < 32; i += 8)
        out[(size_t)(m0 + ty + i) * (C_ * T_) + (n0 + tx)] = tile[tx][ty + i];
}

// ---------------------------------------------------------------------------
// Transpose B: th2 k-half (doh+QH) -> tkT (unit 3b+0; fout dead after trA).
// ---------------------------------------------------------------------------
__global__ __launch_bounds__(256)
void transpose_trB(const _Float16* __restrict__ doh, _Float16* __restrict__ wsh)
{
    const int b = blockIdx.z;
    const _Float16* in  = doh + (size_t)b * 2 * QH_ + QH_;
    _Float16*       out = wsh + (size_t)b * 3 * QH_;
    __shared__ _Float16 tile[32][34];
    const int n0 = blockIdx.x * 32, m0 = blockIdx.y * 32;
    const int tx = threadIdx.x, ty = threadIdx.y;
#pragma unroll
    for (int i = 0; i < 32; i += 8)
        tile[ty + i][tx] = in[(size_t)(n0 + ty + i) * F_ + (m0 + tx)];
    __syncthreads();
#pragma unroll
    for (int i = 0; i < 32; i += 8)
        out[(size_t)(m0 + ty + i) * (C_ * T_) + (n0 + tx)] = tile[tx][ty + i];
}

// ---------------------------------------------------------------------------
// f16 in + f32 residual -> f32 out transpose (final step).
// ---------------------------------------------------------------------------
__global__ __launch_bounds__(256)
void transpose_hf_res(const _Float16* __restrict__ in, const float* __restrict__ res,
                      float* __restrict__ out, int Mo, int No, int si, int sr, int so)
{
    __shared__ _Float16 tile[32][34];
    in  += (size_t)blockIdx.z * si;
    res += (size_t)blockIdx.z * sr;
    out += (size_t)blockIdx.z * so;
    const int n0 = blockIdx.x * 32, m0 = blockIdx.y * 32;
    const int tx = threadIdx.x, ty = threadIdx.y;
#pragma unroll
    for (int i = 0; i < 32; i += 8)
        tile[ty + i][tx] = in[(size_t)(n0 + ty + i) * Mo + (m0 + tx)];
    __syncthreads();
#pragma unroll
    for (int i = 0; i < 32; i += 8) {
        const size_t oidx = (size_t)(m0 + ty + i) * No + (n0 + tx);
        out[oidx] = (float)tile[tx][ty + i] + res[oidx];
    }
}

// ---------------------------------------------------------------------------
// MFMA f16 fused attention — all-f16 I/O, batched.  O may alias Q (in-place):
// each block reads Q only in its own output strip, written after all reads.
// ---------------------------------------------------------------------------
template<int MODE>
__global__ __launch_bounds__(256, 2)
void attn_mfma(const _Float16* __restrict__ Qb, const _Float16* __restrict__ Kb,
               const _Float16* __restrict__ Vb, _Float16* __restrict__ Ob,
               int qs, int ks, int vs, int os)
{
    constexpr int NY  = (MODE == 0) ? 256 : 320;
    constexpr int LD  = (MODE == 0) ? TF_ : T_;
    constexpr int NT  = NY / 16;
    constexpr int NYK = NY / 32;
    constexpr int KS  = 104;
    constexpr int VPS = NY + 24;
    constexpr int KVH = (NY * KS > 96 * VPS) ? NY * KS : 96 * VPS;
    constexpr int NG  = (MODE == 0) ? T_ : F_;
    constexpr int GOFF = (MODE == 0) ? F_ : C_ * T_;

    extern __shared__ _Float16 ldsh[];
    _Float16* KV = ldsh;                 // Kt[NY][KS] -> V[96][VPS]
    _Float16* Pw = ldsh + KVH;           // [4][16][40]

    const int lb    = blockIdx.y;
    const int strip = blockIdx.x / NG;
    const int grp   = blockIdx.x % NG;
    const int m0    = strip * 64;
    const size_t off = (size_t)grp * GOFF;
    const _Float16* Q = Qb + (size_t)lb * qs + off;
    const _Float16* K = Kb + (size_t)lb * ks + off;
    const _Float16* V = Vb + (size_t)lb * vs + off;
    _Float16*       O = Ob + (size_t)lb * os + off;

    const int tid  = threadIdx.x;
    const int lane = tid & 63, wid = tid >> 6;
    const int l16  = lane & 15, lg = lane >> 4;
    const int mw   = wid * 16;
    const float scale = 0.10206207261596575f;   // 1/sqrt(96)

    for (int e = tid; e < NY * 12; e += 256) {
        const int yy = e % NY, k0 = (e / NY) * 8;
        const _Float16* kp = K + (size_t)k0 * LD + yy;
        h8 hv;
#pragma unroll
        for (int j = 0; j < 8; ++j) hv[j] = kp[(size_t)j * LD];
        *(h8*)&KV[yy * KS + k0] = hv;
    }

    h8 aQ[3];
#pragma unroll
    for (int kk = 0; kk < 3; ++kk) {
        const _Float16* qp = Q + (size_t)(kk * 32 + lg * 8) * LD + m0 + mw + l16;
#pragma unroll
        for (int j = 0; j < 8; ++j) aQ[kk][j] = qp[(size_t)j * LD];
    }
    __syncthreads();

    f32x4 sacc[NT];
#pragma unroll
    for (int t = 0; t < NT; ++t) sacc[t] = (f32x4){0.f, 0.f, 0.f, 0.f};
#pragma unroll
    for (int kk = 0; kk < 3; ++kk) {
#pragma unroll
        for (int t = 0; t < NT; ++t) {
            const h8 bK = *(const h8*)&KV[(t * 16 + l16) * KS + kk * 32 + lg * 8];
            sacc[t] = __builtin_amdgcn_mfma_f32_16x16x32_f16(aQ[kk], bK, sacc[t], 0, 0, 0);
        }
    }

#pragma unroll
    for (int r = 0; r < 4; ++r) {
        float mx = sacc[0][r];
#pragma unroll
        for (int t = 1; t < NT; ++t) mx = fmaxf(mx, sacc[t][r]);
        for (int d = 1; d < 16; d <<= 1) mx = fmaxf(mx, __shfl_xor(mx, d));
        float pv[NT];
        float sum = 0.f;
#pragma unroll
        for (int t = 0; t < NT; ++t) {
            pv[t] = __expf((sacc[t][r] - mx) * scale); sum += pv[t];
        }
        for (int d = 1; d < 16; d <<= 1) sum += __shfl_xor(sum, d);
        const float inv = 1.f / sum;
#pragma unroll
        for (int t = 0; t < NT; ++t) sacc[t][r] = pv[t] * inv;
    }
    __syncthreads();

    constexpr int NY8 = NY / 8;
    for (int e = tid; e < 96 * NY8; e += 256) {
        const int c = e / NY8, y8 = e - c * NY8;
        *(h8*)&KV[c * VPS + y8 * 8] = *(const h8*)(V + (size_t)c * LD + y8 * 8);
    }
    __syncthreads();

    _Float16* Pme = Pw + wid * 640;      // [16][40]
    f32x4 oacc[6];
#pragma unroll
    for (int ct = 0; ct < 6; ++ct) oacc[ct] = (f32x4){0.f, 0.f, 0.f, 0.f};

#pragma unroll
    for (int yk = 0; yk < NYK; ++yk) {
#pragma unroll
        for (int h = 0; h < 2; ++h)
#pragma unroll
            for (int r = 0; r < 4; ++r)
                Pme[(lg * 4 + r) * 40 + h * 16 + l16] = (_Float16)sacc[2 * yk + h][r];
        const h8 pf = *(const h8*)&Pme[l16 * 40 + lg * 8];   // in-wave DS order
#pragma unroll
        for (int ct = 0; ct < 6; ++ct) {
            const h8 av = *(const h8*)&KV[(ct * 16 + l16) * VPS + yk * 32 + lg * 8];
            oacc[ct] = __builtin_amdgcn_mfma_f32_16x16x32_f16(av, pf, oacc[ct], 0, 0, 0);
        }
    }
#pragma unroll
    for (int ct = 0; ct < 6; ++ct)
#pragma unroll
        for (int r = 0; r < 4; ++r)
            O[(size_t)(ct * 16 + lg * 4 + r) * LD + m0 + mw + l16] = (_Float16)oacc[ct][r];
}

// ---------------------------------------------------------------------------
extern "C" void kernel_launch(void* const* d_in, const int* in_sizes, int n_in,
                              void* d_out, int out_size, void* d_ws, size_t ws_size,
                              hipStream_t stream)
{
    const float* inp = (const float*)d_in[0];
    const float* W_f = (const float*)d_in[1];  const float* b_f = (const float*)d_in[2];
    const float* g_f = (const float*)d_in[3];  const float* be_f = (const float*)d_in[4];
    const float* m_f = (const float*)d_in[5];  const float* v_f = (const float*)d_in[6];
    const float* a_f = (const float*)d_in[7];
    const float* W_t = (const float*)d_in[8];  const float* b_t = (const float*)d_in[9];
    const float* g_t = (const float*)d_in[10]; const float* be_t = (const float*)d_in[11];
    const float* m_t = (const float*)d_in[12]; const float* v_t = (const float*)d_in[13];
    const float* a_t = (const float*)d_in[14];
    const float* W_p = (const float*)d_in[15]; const float* b_p = (const float*)d_in[16];
    const float* g_p = (const float*)d_in[17]; const float* be_p = (const float*)d_in[18];
    const float* m_p = (const float*)d_in[19]; const float* v_p = (const float*)d_in[20];
    const float* a_p = (const float*)d_in[21];

    hipFuncSetAttribute((const void*)conv_ft,
                        hipFuncAttributeMaxDynamicSharedMemorySize, 25600);
    hipFuncSetAttribute((const void*)conv_p,
                        hipFuncAttributeMaxDynamicSharedMemorySize, 33280);
    hipFuncSetAttribute((const void*)attn_mfma<0>,
                        hipFuncAttributeMaxDynamicSharedMemorySize, 58880);
    hipFuncSetAttribute((const void*)attn_mfma<1>,
                        hipFuncAttributeMaxDynamicSharedMemorySize, 71680);

    // Unit plan per batch b (f16 units of QH_ elems, stride 3*QH_):
    //  3b+0: fqkv Q -> fout (attn0 in-place) -> [trA] -> tkT -> tmp
    //  3b+1: fqkv K -> foutT (trA)
    //  3b+2: fqkv V -> tqT (trA) -> tout (attn1 in-place)
    //  d_out slice (2 f16 units/batch): th2 q,k halves.
    constexpr int QH = (int)QH_;
    const size_t need4 = (size_t)12 * QH * 2 + (size_t)WTOT * 2 + 1152 * 4 + 4096;
    const int G = (ws_size >= need4) ? 4 : 2;     // batches per pass

    _Float16* wsh  = (_Float16*)d_ws;
    _Float16* wsp  = wsh + (size_t)3 * G * QH;    // W-split tail
    float*    scsh = (float*)(wsp + WTOT);

    prep_kernel<<<dim3(128), dim3(256), 0, stream>>>(
        W_f, W_t, W_p, b_f, g_f, be_f, m_f, v_f,
        b_t, g_t, be_t, m_t, v_t, b_p, g_p, be_p, m_p, v_p, wsp, scsh);

    for (int p = 0; p < B_ / G; ++p) {
        const float* xb  = inp + (size_t)p * G * QH;
        float*       dob = (float*)d_out + (size_t)p * G * QH;
        _Float16*    doh = (_Float16*)dob;        // th2 (2 units/batch)

        // 1. fused conv_f + conv_t: fqkv -> ws, th2 -> d_out slice
        conv_ft<<<dim3(1280, G), dim3(256), 25600, stream>>>(
            xb, wsp, scsh, a_f, a_t, wsh, doh, QH, 3 * QH, 2 * QH);
        // 2. f-attention, O in-place over Q third
        attn_mfma<0><<<dim3(T_ * (F_ / 64), G), dim3(256), 58880, stream>>>(
            wsh, wsh + QH_, wsh + 2 * QH_, wsh, 3 * QH, 3 * QH, 3 * QH, 3 * QH);
        // 3. trA: fout -> foutT (3b+1), th2 q -> tqT (3b+2)
        transpose_trA<<<dim3(960, 8, 2 * G), dim3(32, 8), 0, stream>>>(doh, wsh);
        // 4. trB: th2 k -> tkT (3b+0; fout dead)
        transpose_trB<<<dim3(960, 8, G), dim3(32, 8), 0, stream>>>(doh, wsh);
        // 5. t-attention: Q=tqT(3b+2), K=tkT(3b+0), V=foutT(3b+1), O in-place
        attn_mfma<1><<<dim3(F_ * (T_ / 64), G), dim3(256), 71680, stream>>>(
            wsh + 2 * QH_, wsh, wsh + QH_, wsh + 2 * QH_,
            3 * QH, 3 * QH, 3 * QH, 3 * QH);
        // 6. conv_p(tout = 3b+2) -> tmp (3b+0; tkT dead)
        conv_p<<<dim3(F_ * 2, G), dim3(256), 33280, stream>>>(
            wsh + 2 * QH_, wsp, scsh, a_p, wsh, 3 * QH, 3 * QH);
        // 7. out = transpose(tmp) + inp (th2 dead)
        transpose_hf_res<<<dim3(8, 960, G), dim3(32, 8), 0, stream>>>(
            wsh, xb, dob, C_ * T_, F_, 3 * QH, QH, QH);
    }
}